// Round 1
// baseline (480.516 us; speedup 1.0000x reference)
//
#include <hip/hip_runtime.h>
#include <cstdint>
#include <cstddef>
#include <math.h>

#define TOKENS 16384
#define DIM    4096
#define NE     64
#define MT     128          // tokens per block tile
#define KT     32           // k elements staged per step
#define KT4    (KT/4)       // float4 per row = 8
#define X_F4   (MT*KT4)     // 1024 float4 per x buffer
#define W_F4   (NE*KT4)     // 512  float4 per w buffer

static_assert(TOKENS % MT == 0, "tile");

__device__ __forceinline__ int swz(int row) { return (row >> 2) & 7; }

__device__ __forceinline__ void gload16(const void* g, void* l) {
  __builtin_amdgcn_global_load_lds(
      (const __attribute__((address_space(1))) void*)g,
      (__attribute__((address_space(3))) void*)l, 16, 0, 0);
}

// GEMM: logits_partial[token][expert] for one K-half.
// grid = 256 (128 m-tiles x 2 k-halves) or 128 (no split), block = 256.
__global__ __launch_bounds__(256, 1)
void dr_gemm(const float* __restrict__ x, const float* __restrict__ gw,
             float* __restrict__ p0, float* __restrict__ p1, int steps)
{
  __shared__ float4 xs4[2 * X_F4];
  __shared__ float4 ws4[2 * W_F4];

  const int t    = threadIdx.x;
  const int lane = t & 63;
  const int wv   = t >> 6;     // wave 0..3
  const int ng   = t & 15;     // expert-group thread (4 experts)
  const int mg   = t >> 4;     // token-group thread (8 tokens)

  const int bm    = blockIdx.x & 127;
  const int h     = blockIdx.x >> 7;
  const int kbase = h * steps * KT;
  float* __restrict__ dst = h ? p1 : p0;

  // --- staging constants (global byte offsets exclude the per-step k advance) ---
  size_t xoff[4]; int xlds[4];
#pragma unroll
  for (int r = 0; r < 4; ++r) {
    int row = r * 32 + wv * 8 + (lane >> 3);          // 0..127
    int c4  = (lane & 7) ^ swz(row);                  // pre-swizzled source column
    xoff[r] = ((size_t)(bm * MT + row) * DIM + kbase + 4 * c4) * sizeof(float);
    xlds[r] = (r * 32 + wv * 8) * KT4;                // wave-uniform LDS base (float4)
  }
  size_t woff[2]; int wlds[2];
#pragma unroll
  for (int r = 0; r < 2; ++r) {
    int row = r * 32 + wv * 8 + (lane >> 3);          // 0..63
    int c4  = (lane & 7) ^ swz(row);
    woff[r] = ((size_t)row * DIM + kbase + 4 * c4) * sizeof(float);
    wlds[r] = (r * 32 + wv * 8) * KT4;
  }

  const char* xb = (const char*)x;
  const char* wb = (const char*)gw;

  auto stage = [&](int buf, int sidx) {
    size_t kb = (size_t)sidx * KT * sizeof(float);
#pragma unroll
    for (int r = 0; r < 4; ++r)
      gload16(xb + xoff[r] + kb, (void*)(xs4 + buf * X_F4 + xlds[r]));
#pragma unroll
    for (int r = 0; r < 2; ++r)
      gload16(wb + woff[r] + kb, (void*)(ws4 + buf * W_F4 + wlds[r]));
  };

  float acc[8][4], accl[8][4];
#pragma unroll
  for (int i = 0; i < 8; ++i)
#pragma unroll
    for (int j = 0; j < 4; ++j) { acc[i][j] = 0.f; accl[i][j] = 0.f; }

  stage(0, 0);
  __syncthreads();

  int buf = 0;
  for (int s = 0; s < steps; ++s) {
    if (s + 1 < steps) stage(buf ^ 1, s + 1);   // async prefetch, drained at barrier
    const float4* X = xs4 + buf * X_F4;
    const float4* W = ws4 + buf * W_F4;
#pragma unroll
    for (int c4 = 0; c4 < KT4; ++c4) {
      float4 bv[4];
#pragma unroll
      for (int j = 0; j < 4; ++j) {
        int row = 4 * ng + j;
        bv[j] = W[row * KT4 + (c4 ^ swz(row))];
      }
#pragma unroll
      for (int i = 0; i < 8; ++i) {
        int row = 8 * mg + i;
        float4 a = X[row * KT4 + (c4 ^ swz(row))];
#pragma unroll
        for (int j = 0; j < 4; ++j) {
          accl[i][j] = fmaf(a.x, bv[j].x, accl[i][j]);
          accl[i][j] = fmaf(a.y, bv[j].y, accl[i][j]);
          accl[i][j] = fmaf(a.z, bv[j].z, accl[i][j]);
          accl[i][j] = fmaf(a.w, bv[j].w, accl[i][j]);
        }
      }
    }
    // two-level accumulation: fold K-step partial into main acc (cuts rounding drift)
#pragma unroll
    for (int i = 0; i < 8; ++i)
#pragma unroll
      for (int j = 0; j < 4; ++j) { acc[i][j] += accl[i][j]; accl[i][j] = 0.f; }
    __syncthreads();
    buf ^= 1;
  }

  // write partial logits [token][expert], float4 per thread-row
#pragma unroll
  for (int i = 0; i < 8; ++i) {
    int row = bm * MT + 8 * mg + i;
    float4 v = make_float4(acc[i][0], acc[i][1], acc[i][2], acc[i][3]);
    reinterpret_cast<float4*>(dst)[(size_t)row * (NE / 4) + ng] = v;
  }
}

// Combine: add K-halves, scale by 1/(|T|+eps), top-2, softmax, scatter.
// One wave per token; lane == expert. grid = TOKENS/4, block = 256.
__global__ __launch_bounds__(256)
void dr_combine(const float* __restrict__ p0, const float* __restrict__ p1, int two,
                const float* __restrict__ temp, float* __restrict__ outr,
                float* __restrict__ outi)
{
  int tok = blockIdx.x * 4 + (threadIdx.x >> 6);
  int e   = threadIdx.x & 63;
  float invT = 1.0f / (fabsf(temp[0]) + 1e-5f);
  size_t base = (size_t)tok * NE + e;
  float v = p0[base];
  if (two) v += p1[base];
  v *= invT;

  // top-1 (ties -> lower index, matching lax.top_k)
  float bv = v; int bi = e;
#pragma unroll
  for (int off = 32; off; off >>= 1) {
    float ov = __shfl_xor(bv, off);
    int   oi = __shfl_xor(bi, off);
    if (ov > bv || (ov == bv && oi < bi)) { bv = ov; bi = oi; }
  }
  float v0 = bv; int i0 = bi;

  // top-2
  float vm = (e == i0) ? -INFINITY : v;
  bv = vm; bi = e;
#pragma unroll
  for (int off = 32; off; off >>= 1) {
    float ov = __shfl_xor(bv, off);
    int   oi = __shfl_xor(bi, off);
    if (ov > bv || (ov == bv && oi < bi)) { bv = ov; bi = oi; }
  }
  float v1 = bv; int i1 = bi;

  float ed = expf(v1 - v0);            // d <= 0, already temperature-scaled
  float s  = 1.0f / (1.0f + ed);
  float w0 = s, w1 = ed * s;

  outr[base] = (e == i0) ? w0 : (e == i1) ? w1 : 0.0f;
  if (e == 0) {
    outi[(size_t)tok * 2]     = (float)i0;   // harness reads flat buffer as fp32
    outi[(size_t)tok * 2 + 1] = (float)i1;
  }
}

extern "C" void kernel_launch(void* const* d_in, const int* in_sizes, int n_in,
                              void* d_out, int out_size, void* d_ws, size_t ws_size,
                              hipStream_t stream)
{
  const float* x  = (const float*)d_in[0];
  const float* gw = (const float*)d_in[1];
  const float* tp = (const float*)d_in[2];
  float* outr = (float*)d_out;
  float* outi = outr + (size_t)TOKENS * NE;
  float* p1   = (float*)d_ws;

  bool split = ws_size >= (size_t)TOKENS * NE * sizeof(float);
  if (split) {
    // 2-way split-K: half 0 partials land in the routing region of d_out (scratch),
    // half 1 in d_ws; combine overwrites d_out with the final routing matrix.
    dr_gemm<<<dim3(256), dim3(256), 0, stream>>>(x, gw, outr, p1, 64);
    dr_combine<<<dim3(TOKENS / 4), dim3(256), 0, stream>>>(outr, p1, 1, tp, outr, outi);
  } else {
    dr_gemm<<<dim3(128), dim3(256), 0, stream>>>(x, gw, outr, (float*)nullptr, 128);
    dr_combine<<<dim3(TOKENS / 4), dim3(256), 0, stream>>>(outr, outr, 0, tp, outr, outi);
  }
}